// Round 7
// baseline (475.998 us; speedup 1.0000x reference)
//
#include <hip/hip_runtime.h>
#include <hip/hip_bf16.h>

#define NN 8192
#define DD 128

typedef __attribute__((ext_vector_type(8))) short short8;
typedef __attribute__((ext_vector_type(4))) float f32x4;
typedef unsigned int u32;

__device__ __forceinline__ ushort f2bf(float f) {
    __hip_bfloat16 h = __float2bfloat16(f);
    return *(ushort*)&h;
}
__device__ __forceinline__ float asf(u32 u) {
    union { u32 i; float f; } v; v.i = u; return v.f;
}
__device__ __forceinline__ u32 asu(float f) {
    union { float f; u32 i; } v; v.f = f; return v.i;
}

// ---------------- K1f: Wh = X@Ws fused with transpose + per-row scalars ------
__global__ __launch_bounds__(256) void k1_fused(
    const float* __restrict__ X, const float* __restrict__ Ws,
    const float* __restrict__ a, ushort* __restrict__ WhT,
    float* __restrict__ C1, float* __restrict__ C1s, u32* __restrict__ E2bf) {
    __shared__ float lWs[128 * 132];   // overlaid by lT[128][33] after use
    __shared__ float lX[32 * 132];
    __shared__ float la[256];
    int t = threadIdx.x, bx = blockIdx.x;
    int i0 = bx * 32;
    const float4* Ws4 = (const float4*)Ws;
    const float4* X4 = (const float4*)X;
    la[t] = a[t];
    for (int j = 0; j < 16; ++j) {
        int u = j * 256 + t;
        int k = u >> 5, c4 = u & 31;
        *(float4*)&lWs[k * 132 + c4 * 4] = Ws4[u];
    }
    for (int j = 0; j < 4; ++j) {
        int u = j * 256 + t;
        int r = u >> 5, c4 = u & 31;
        *(float4*)&lX[r * 132 + c4 * 4] = X4[bx * 1024 + u];
    }
    __syncthreads();
    int r0 = (t >> 5) * 4, c0 = (t & 31) * 4;
    float acc[4][4];
#pragma unroll
    for (int i = 0; i < 4; ++i)
#pragma unroll
        for (int j = 0; j < 4; ++j) acc[i][j] = 0.f;
#pragma unroll 4
    for (int k = 0; k < 128; ++k) {
        float4 wv = *(const float4*)&lWs[k * 132 + c0];
        float x0 = lX[(r0 + 0) * 132 + k];
        float x1 = lX[(r0 + 1) * 132 + k];
        float x2 = lX[(r0 + 2) * 132 + k];
        float x3 = lX[(r0 + 3) * 132 + k];
#pragma unroll
        for (int j = 0; j < 4; ++j) {
            acc[0][j] += x0 * ((const float*)&wv)[j];
            acc[1][j] += x1 * ((const float*)&wv)[j];
            acc[2][j] += x2 * ((const float*)&wv)[j];
            acc[3][j] += x3 * ((const float*)&wv)[j];
        }
    }
    __syncthreads();
    float* lT = lWs;   // [d=128][r=32] pad 33
#pragma unroll
    for (int i = 0; i < 4; ++i)
#pragma unroll
        for (int j = 0; j < 4; ++j) lT[(c0 + j) * 33 + r0 + i] = acc[i][j];
    __syncthreads();
    if (t < 128) {
        int r = t >> 2, q = t & 3;
        float s1 = 0.f, s2 = 0.f;
        for (int j = 0; j < 32; ++j) {
            int d = q * 32 + j;
            float v = lT[d * 33 + r];
            s1 += v * la[d];
            s2 += v * la[128 + d];
        }
        s1 += __shfl_xor(s1, 1); s1 += __shfl_xor(s1, 2);
        s2 += __shfl_xor(s2, 1); s2 += __shfl_xor(s2, 2);
        if (q == 0) {
            int i = i0 + r;
            C1[i]  = __expf(s1);
            C1s[i] = __expf(0.2f * s1);
            u32 pe = (u32)f2bf(__expf(s2));
            u32 ne = (u32)f2bf(__expf(0.2f * s2));
            E2bf[i] = pe | (ne << 16);
        }
    }
    int d = t >> 1, hf = t & 1;
    __attribute__((aligned(16))) ushort tmp[16];
#pragma unroll
    for (int s = 0; s < 16; ++s) tmp[s] = f2bf(lT[d * 33 + hf * 16 + s]);
    uint4* dst = (uint4*)&WhT[(size_t)d * NN + i0 + hf * 16];
    const uint4* srcv = (const uint4*)tmp;
    dst[0] = srcv[0];
    dst[1] = srcv[1];
}

// ---------------- K3: masked-softmax GEMM, barrier-free K-loop ----------------
// grid (128, 4) x 512 thr (8 waves: g=wv&3 rowgroup of 16, h=wv>>2 col-half of 64).
// Per kt (64 k): 8 B-loads (L2-resident WhT) issued FIRST, then 4 A-loads for
// kt+1 (register double-buffer) -> waiting on B keeps next-A in flight; A has a
// full-iteration prefetch distance. No __syncthreads in the loop: free-running
// waves self-stagger, 4 waves/SIMD hide latency. E2 bf16-pair per col in LDS.
// Row sums via ones-MFMA on h==0 waves only. w packed to bf16 by truncation
// (bias cancels between numerator and softmax denominator).
__global__ __launch_bounds__(512, 4) void k3_main(
    const int* __restrict__ A, const ushort* __restrict__ WhT,
    const float* __restrict__ C1, const float* __restrict__ C1s,
    const u32* __restrict__ E2bf, float* __restrict__ Hp,
    float* __restrict__ Lp) {

    __shared__ u32 lE[2048];   // 8 KB

    int tid = threadIdx.x;
    int lane = tid & 63;
    int wv = tid >> 6;
    int g = wv & 3;
    int h = wv >> 2;
    int n = lane & 15;
    int kg = lane >> 4;

    int bx = blockIdx.x;
    int kb = blockIdx.y;
    int row = bx * 64 + g * 16 + n;
    int kbase = kb * 2048;

#pragma unroll
    for (int j = 0; j < 4; ++j) lE[tid + j * 512] = E2bf[kbase + tid + j * 512];

    float c1 = C1[row], c1s = C1s[row];
    const int* Arow = A + (size_t)row * NN + kbase + kg * 8;
    const ushort* Bc0 = WhT + (size_t)(h * 64 +  0 + n) * NN + kbase + kg * 8;
    const ushort* Bc1 = WhT + (size_t)(h * 64 + 16 + n) * NN + kbase + kg * 8;
    const ushort* Bc2 = WhT + (size_t)(h * 64 + 32 + n) * NN + kbase + kg * 8;
    const ushort* Bc3 = WhT + (size_t)(h * 64 + 48 + n) * NN + kbase + kg * 8;

    short8 ones;
#pragma unroll
    for (int j = 0; j < 8; ++j) ones[j] = (short)0x3F80;

    f32x4 acc0 = (f32x4){0.f, 0.f, 0.f, 0.f};
    f32x4 acc1 = (f32x4){0.f, 0.f, 0.f, 0.f};
    f32x4 acc2 = (f32x4){0.f, 0.f, 0.f, 0.f};
    f32x4 acc3 = (f32x4){0.f, 0.f, 0.f, 0.f};
    f32x4 accl = (f32x4){0.f, 0.f, 0.f, 0.f};

    __syncthreads();   // lE ready (only barrier in the kernel)

    // A register double-buffer; prologue loads kt=0
    int4 Ar[2][4];
    Ar[0][0] = *(const int4*)(Arow);
    Ar[0][1] = *(const int4*)(Arow + 4);
    Ar[0][2] = *(const int4*)(Arow + 32);
    Ar[0][3] = *(const int4*)(Arow + 36);

#pragma unroll 2
    for (int kt = 0; kt < 32; ++kt) {
        int b = kt & 1;
        int ko = kt * 64;
        // B for THIS kt (L2) — issued first
        short8 B00 = *(const short8*)(Bc0 + ko);
        short8 B10 = *(const short8*)(Bc1 + ko);
        short8 B20 = *(const short8*)(Bc2 + ko);
        short8 B30 = *(const short8*)(Bc3 + ko);
        short8 B01 = *(const short8*)(Bc0 + ko + 32);
        short8 B11 = *(const short8*)(Bc1 + ko + 32);
        short8 B21 = *(const short8*)(Bc2 + ko + 32);
        short8 B31 = *(const short8*)(Bc3 + ko + 32);
        // A for NEXT kt — issued after B so B-waits leave these in flight
        if (kt < 31) {
            Ar[b ^ 1][0] = *(const int4*)(Arow + ko + 64);
            Ar[b ^ 1][1] = *(const int4*)(Arow + ko + 68);
            Ar[b ^ 1][2] = *(const int4*)(Arow + ko + 96);
            Ar[b ^ 1][3] = *(const int4*)(Arow + ko + 100);
        }
#pragma unroll
        for (int tp = 0; tp < 2; ++tp) {
            int ke = ko + tp * 32 + kg * 8;
            uint4 e0 = *(const uint4*)&lE[ke];
            uint4 e1 = *(const uint4*)&lE[ke + 4];
            int am[8]; u32 ev[8];
            *(int4*)(am) = Ar[b][tp * 2];
            *(int4*)(am + 4) = Ar[b][tp * 2 + 1];
            *(uint4*)(ev) = e0; *(uint4*)(ev + 4) = e1;
            u32 wb[8];
#pragma unroll
            for (int u = 0; u < 8; ++u) {
                float ep = asf(ev[u] << 16);
                float en = asf(ev[u] & 0xFFFF0000u);
                float w = fmaxf(c1 * ep, c1s * en);
                w = am[u] ? w : 0.f;
                wb[u] = asu(w);
            }
            short8 af;
#pragma unroll
            for (int p = 0; p < 4; ++p)
                ((u32*)&af)[p] = __builtin_amdgcn_perm(wb[2 * p + 1], wb[2 * p], 0x07060302);
            acc0 = __builtin_amdgcn_mfma_f32_16x16x32_bf16(af, tp ? B01 : B00, acc0, 0, 0, 0);
            acc1 = __builtin_amdgcn_mfma_f32_16x16x32_bf16(af, tp ? B11 : B10, acc1, 0, 0, 0);
            acc2 = __builtin_amdgcn_mfma_f32_16x16x32_bf16(af, tp ? B21 : B20, acc2, 0, 0, 0);
            acc3 = __builtin_amdgcn_mfma_f32_16x16x32_bf16(af, tp ? B31 : B30, acc3, 0, 0, 0);
            if (h == 0)
                accl = __builtin_amdgcn_mfma_f32_16x16x32_bf16(af, ones, accl, 0, 0, 0);
        }
    }

    // epilogue. C/D layout: col = lane&15, row = (lane>>4)*4 + reg  [m89]
    if (h == 0 && n == 0) {
#pragma unroll
        for (int r = 0; r < 4; ++r)
            Lp[(size_t)kb * NN + bx * 64 + g * 16 + kg * 4 + r] = accl[r];
    }
    float* Hpb = Hp + (size_t)kb * (NN * DD);
#pragma unroll
    for (int r = 0; r < 4; ++r) {
        int orow = bx * 64 + g * 16 + kg * 4 + r;
        Hpb[(size_t)orow * DD + h * 64 + n]      = acc0[r];
        Hpb[(size_t)orow * DD + h * 64 + 16 + n] = acc1[r];
        Hpb[(size_t)orow * DD + h * 64 + 32 + n] = acc2[r];
        Hpb[(size_t)orow * DD + h * 64 + 48 + n] = acc3[r];
    }
}

// ---------------- K4: combine split-K partials, normalize ----------------
__global__ void k4_final(const float* __restrict__ Hp, const float* __restrict__ Lp,
                         float* __restrict__ out) {
    int idx = blockIdx.x * 256 + threadIdx.x;
    int i = idx >> 7;
    float sv = Hp[idx] + Hp[1048576 + idx] + Hp[2097152 + idx] + Hp[3145728 + idx];
    float l = Lp[i] + Lp[8192 + i] + Lp[16384 + i] + Lp[24576 + i];
    out[idx] = sv / l;
}

extern "C" void kernel_launch(void* const* d_in, const int* in_sizes, int n_in,
                              void* d_out, int out_size, void* d_ws, size_t ws_size,
                              hipStream_t stream) {
    const int*   A  = (const int*)d_in[0];
    const float* X  = (const float*)d_in[1];
    const float* Ws = (const float*)d_in[2];
    const float* a  = (const float*)d_in[3];
    float* out = (float*)d_out;

    char* ws = (char*)d_ws;
    ushort* WhT  = (ushort*)(ws);                        // 2 MB
    float*  C1   = (float*)(ws + (2u << 20));
    float*  C1s  = (float*)(ws + (2u << 20) + (32u << 10));
    u32*    E2bf = (u32*)(ws + (2u << 20) + (64u << 10));
    float*  Lp   = (float*)(ws + (2u << 20) + (96u << 10));
    float*  Hp   = (float*)(ws + (4u << 20));            // 16 MB

    k1_fused<<<256, 256, 0, stream>>>(X, Ws, a, WhT, C1, C1s, E2bf);
    k3_main<<<dim3(128, 4), 512, 0, stream>>>(A, WhT, C1, C1s, E2bf, Hp, Lp);
    k4_final<<<4096, 256, 0, stream>>>(Hp, Lp, out);
}